// Round 1
// baseline (64.292 us; speedup 1.0000x reference)
//
#include <hip/hip_runtime.h>
#include <math.h>

#define HH 256
#define WW 256
#define CC 3
#define HW (HH*WW)

__global__ __launch_bounds__(256) void adaptive_log_kernel(
    const float* __restrict__ x, const float* __restrict__ foa,
    float* __restrict__ out)
{
    const int p  = blockIdx.x * 256 + threadIdx.x;   // pixel index within image
    const int b  = blockIdx.y;                       // batch
    const int py = p >> 8;                           // / WW
    const int px = p & (WW - 1);

    // ---- per-pixel sigma / common factor ----
    const float fx = foa[2*b + 0];
    const float fy = foa[2*b + 1];
    const float ddx = (float)px - fx;
    const float ddy = (float)py - fy;
    const float dist = sqrtf(ddx*ddx + ddy*ddy);
    const float inv_diag = 1.0f / 362.03867196751236f;  // 1/sqrt(256^2+256^2)
    const float dn = dist * inv_diag;
    const float sigma = 0.5f + 9.5f * dn;               // (1-dn)*0.5 + dn*10
    const float s2 = sigma * sigma;
    const float inv2s2 = 0.5f / s2;
    const float factor = -1.0f / ((float)M_PI * s2 * s2);
    const float common = factor * sqrtf(sigma) * dist;

    // ---- 16 distinct r^2 values in the 9x9 window ----
    float w[33];
    const int r2v[16] = {0,1,2,4,5,8,9,10,13,16,17,18,20,25,26,32};
    #pragma unroll
    for (int i = 0; i < 16; ++i) {
        const float t = (float)r2v[i] * inv2s2;
        w[r2v[i]] = common * (1.0f - t) * __expf(-t);
    }

    // ---- reflected row/col indices (pad=4, reflect mode: edge excluded) ----
    int xi[9], yi[9];
    #pragma unroll
    for (int i = 0; i < 9; ++i) {
        int xx = px + i - 4;
        xx = (xx < 0) ? -xx : xx;
        xx = (xx > WW-1) ? (2*(WW-1) - xx) : xx;
        xi[i] = xx;
        int yy = py + i - 4;
        yy = (yy < 0) ? -yy : yy;
        yy = (yy > HH-1) ? (2*(HH-1) - yy) : yy;
        yi[i] = yy * WW;
    }

    // ---- 9x9 conv, 3 channels sharing weights ----
    const float* xb = x + (size_t)b * (CC*HW);
    float a0 = 0.f, a1 = 0.f, a2 = 0.f;
    #pragma unroll
    for (int a = 0; a < 9; ++a) {
        const int dy = a - 4;
        #pragma unroll
        for (int bb = 0; bb < 9; ++bb) {
            const int dx = bb - 4;
            const float wv = w[dy*dy + dx*dx];   // compile-time index -> VGPR
            const int off = yi[a] + xi[bb];
            a0 += wv * xb[off];
            a1 += wv * xb[off + HW];
            a2 += wv * xb[off + 2*HW];
        }
    }

    float* ob = out + (size_t)b * (CC*HW);
    ob[p]          = a0;
    ob[p + HW]     = a1;
    ob[p + 2*HW]   = a2;
}

extern "C" void kernel_launch(void* const* d_in, const int* in_sizes, int n_in,
                              void* d_out, int out_size, void* d_ws, size_t ws_size,
                              hipStream_t stream) {
    const float* x   = (const float*)d_in[0];   // [4,3,256,256] f32
    const float* foa = (const float*)d_in[1];   // [4,2] f32
    float* out = (float*)d_out;                 // [4,3,256,256] f32

    dim3 grid(HW / 256, 4);
    dim3 block(256);
    adaptive_log_kernel<<<grid, block, 0, stream>>>(x, foa, out);
}